// Round 16
// baseline (40.168 us; speedup 1.0000x reference)
//
#include <hip/hip_runtime.h>

#define MT    132      // padded (M+1): 129 valid + 3 zero pad
#define NSEQ  512
#define LSEQ  256
#define MM    128      // M
#define NROW  129      // M+1
#define BETA  10.0     // reweighting: track a * e^{BETA*(t - mp)}
#define LOG2E 1.4426950408889634
#define LN2   0.6931471805599453

// per-mp transition tables (indexed by i = chain/source index), REWEIGHTED.
// T_W = backward init vector e^{beta*mp} scaled by 2^-923 (fits fp64 exactly).
enum { T_TMX=0, T_TIX, T_TMEQ0, T_TIEQ0, T_TMEQ1, T_TIEQ1,
       T_ENT0, T_ENT1, T_STP, T_I0, T_I1, T_W, T_COUNT };     // 12

// ws layout: [tabd doubles][emd doubles]
#define TABD_CNT   (T_COUNT*MT)
#define EMD_OFF    (TABD_CNT*8)
// emission layout (conflict-free, r14): emd2[tok][j][lane], double2
// {match,ins}, col = 3*lane + j, lane 0..43. Row = 2112 B.
#define EMD_CNT    (25*3*44*2)            // 6600 doubles = 52800 B
#define EMD_ROW_B  (3*44*16)              // 2112 bytes per token row
#define EMD_J_B    (44*16)                // 704 bytes per j-block

// Pin a loop-invariant value into a VGPR: the asm result is opaque, so the
// allocator cannot rematerialize the originating load inside the loop.
#define PIN3(a) asm volatile("" : "+v"(a[0]), "+v"(a[1]), "+v"(a[2]))
#define PIN1(x) asm volatile("" : "+v"(x))

// DPP ctrl (gfx9/CDNA): WAVE_SHR1=0x138 (lane l <- l-1), WAVE_SHL1=0x130
// (lane l <- l+1), ROW_SHR:d=0x110+d, ROW_BCAST15/31=0x142/3.
// All HW-verified rounds 4-15 (absmax 0.0 with these paths live).
template <int CTRL, int RMASK, bool BC>
__device__ __forceinline__ double dpp_d(double v) {
  int lo = __double2loint(v), hi = __double2hiint(v);
  lo = __builtin_amdgcn_update_dpp(0, lo, CTRL, RMASK, 0xF, BC);
  hi = __builtin_amdgcn_update_dpp(0, hi, CTRL, RMASK, 0xF, BC);
  return __hiloint2double(hi, lo);
}

__device__ __forceinline__ double lse2d(double a, double b) {
  double m = fmax(a, b);
  return m + log(exp(a - m) + exp(b - m));
}

// -------------------------------------------------------------- prep ------
__global__ void prep_kernel(const float* __restrict__ anc,
                            const float* __restrict__ insq,
                            const float* __restrict__ rr,
                            const float* __restrict__ uu,
                            double* __restrict__ tabd,
                            double* __restrict__ emd) {
  const int tid = threadIdx.x;
  __shared__ double ls[T_COUNT*MT];
  if (tid < MT) {
    double v[T_COUNT];
#pragma unroll
    for (int k = 0; k < T_COUNT; ++k) v[k] = 0.0;
    if (tid <= MM) {
      const int m = tid;
      double rn[3][2], un[3][2];
#pragma unroll
      for (int j = 0; j < 3; ++j) {
        double a0 = (double)rr[(m*3+j)*2+0], a1 = (double)rr[(m*3+j)*2+1];
        double l  = lse2d(a0, a1);
        rn[j][0] = a0 - l; rn[j][1] = a1 - l;
        double b0 = (double)uu[(m*3+j)*2+0], b1 = (double)uu[(m*3+j)*2+1];
        double l2 = lse2d(b0, b1);
        un[j][0] = b0 - l2; un[j][1] = b1 - l2;
      }
      v[T_TMX]   = exp(rn[0][0] + un[0][1] - BETA);
      v[T_TIX]   = exp(rn[1][0] + un[1][1]);
      v[T_TMEQ0] = exp(rn[0][0] + un[0][0]);
      v[T_TIEQ0] = exp(rn[1][0] + un[1][0] + BETA);
      v[T_TMEQ1] = exp(rn[0][1]);
      v[T_TIEQ1] = exp(rn[1][1] + BETA);
      v[T_ENT0]  = exp(rn[2][0] + un[2][0]);
      v[T_ENT1]  = exp(rn[2][1]);
      v[T_STP]   = exp(rn[2][0] + un[2][1] - BETA);
      v[T_W]     = exp2(BETA*LOG2E*(double)m - 923.0);  // e^{beta*mp} * 2^-923
    }
#pragma unroll
    for (int k = 0; k < T_COUNT; ++k) ls[k*MT + tid] = v[k];
  }
  __syncthreads();

  if (tid == 0) {   // initial dist (virtual source i=0,j=0): EXACT full chain
    ls[T_I0*MT+0] = ls[T_TMEQ0*MT+0];
    ls[T_I1*MT+0] = ls[T_TMEQ1*MT+0];
    double c = ls[T_TMX*MT+0];
    for (int mp = 1; mp <= MM; ++mp) {
      ls[T_I0*MT+mp] = c * ls[T_ENT0*MT+mp];
      ls[T_I1*MT+mp] = c * ls[T_ENT1*MT+mp];
      c *= ls[T_STP*MT+mp];
    }
  }
  __syncthreads();

  for (int i = tid; i < T_COUNT*MT; i += blockDim.x) tabd[i] = ls[i];

  // emission table, conflict-free layout: dst[d*132 + j*44 + lane] (double2)
  if (tid < MT) {
    const int col = tid, j = col % 3, ln = col / 3;
    double2* dst = ((double2*)emd) + (j*44 + ln);
    if (col <= MM) {
      const float* sa = anc  + col*24;
      const float* si = insq + col*24;
      float mxa = -1e30f, mxi = -1e30f;
      for (int d = 0; d < 24; ++d) { mxa = fmaxf(mxa, sa[d]); mxi = fmaxf(mxi, si[d]); }
      float ssa = 0.f, ssi = 0.f;
      for (int d = 0; d < 24; ++d) { ssa += __expf(sa[d]-mxa); ssi += __expf(si[d]-mxi); }
      float ia = 1.f/ssa, ii = 1.f/ssi;
      for (int d = 0; d < 24; ++d) {
        double2 e;
        e.x = (double)(__expf(sa[d]-mxa)*ia);
        e.y = (double)(__expf(si[d]-mxi)*ii);
        dst[d*132] = e;
      }
      double2 one; one.x = 1.0; one.y = 1.0;
      dst[24*132] = one;                 // masked token row
    } else {
      double2 z; z.x = 0.0; z.y = 0.0;
      for (int d = 0; d < 25; ++d) dst[d*132] = z;   // pad cols 129..131
    }
  }
}

// ------------------------------------------------------------- fwd/bwd ----
// r15 structure (2 seqs/block share one LDS emission table; fwd 135 / bwd
// 120 steps) + REGISTER-PINNED loop-invariant tables (the r16 test): the
// anomalously low VGPR_Count (48-68 all session) says the allocator
// remats/parks the 33 per-lane table doubles instead of keeping them live,
// paying hidden per-step latency. PIN forces them into VGPRs.
struct E6 { double2 a, b, c; };

__global__ __launch_bounds__(256, 1)
void fb_kernel(const double* __restrict__ tabd,
               const double* __restrict__ emd,
               const float* __restrict__ data,
               float* __restrict__ out) {
  __shared__ double2 ldsE[EMD_CNT/2];  // 52800 B shared emission table
  __shared__ int     ldsT[2][LSEQ];
  __shared__ double  gbuf[2][64*6];
  __shared__ int     gacc[2];
  const int tid  = threadIdx.x;
  const int lane = tid & 63;
  const int wid  = tid >> 6;
  const int s    = wid >> 1;            // sequence slot within block
  const int role = wid & 1;             // 0 = forward, 1 = backward
  const int n    = blockIdx.x*2 + s;

  // preload emission table (double2 coalesced, all 256 threads)
  {
    const double2* src = (const double2*)emd;
    for (int i = tid; i < EMD_CNT/2; i += 256) ldsE[i] = src[i];
  }
  // token decode: 512 positions (2 seqs), 2 per thread, float4 loads
  for (int pos = tid; pos < 2*LSEQ; pos += 256) {
    const int sq = pos >> 8, pp = pos & (LSEQ-1);
    const float4* p = (const float4*)(data + ((size_t)(blockIdx.x*2 + sq)*LSEQ + pp)*24);
    int tok = 24;
#pragma unroll
    for (int q = 0; q < 6; ++q) {
      float4 v = p[q];
      if (v.x > 0.5f) tok = 4*q+0;
      if (v.y > 0.5f) tok = 4*q+1;
      if (v.z > 0.5f) tok = 4*q+2;
      if (v.w > 0.5f) tok = 4*q+3;
    }
    ldsT[sq][pp] = tok * EMD_ROW_B;
  }
  __syncthreads();

  const int* ldsTs = ldsT[s];
  const int mp0 = 3*lane;
  const int lx  = (lane < 44) ? lane : 43;
  const char* lB = (const char*)ldsE + (size_t)lx*16;
  auto loadEoff = [&](int off) {       // 3 lane-contiguous b128 reads
    E6 e;
    e.a = *(const double2*)(lB + off);               // col 3*lx+0
    e.b = *(const double2*)(lB + off + EMD_J_B);     // col 3*lx+1
    e.c = *(const double2*)(lB + off + 2*EMD_J_B);   // col 3*lx+2
    return e;
  };

  double aM0, aM1, aM2, aI0, aI1, aI2;   // fwd: alpha~; bwd: gamma~
  int acc2i = 0;

  auto RENORM = [&]() {   // exact exponent-only renorm, target max ~= 2^500
    double m = fmax(fmax(fmax(aM0,aM1), fmax(aM2,aI0)), fmax(aI1,aI2));
    m = fmax(m, dpp_d<0x111, 0xF, true >(m));
    m = fmax(m, dpp_d<0x112, 0xF, true >(m));
    m = fmax(m, dpp_d<0x114, 0xF, true >(m));
    m = fmax(m, dpp_d<0x118, 0xF, true >(m));
    m = fmax(m, dpp_d<0x142, 0xA, false>(m));
    m = fmax(m, dpp_d<0x143, 0xC, false>(m));
    int ehi = __builtin_amdgcn_readlane(__double2hiint(m), 63);
    int er  = (ehi >> 20) & 0x7FF;
    int dl  = er ? (1523 - er) : 0;
    acc2i -= dl;
    double sc = __hiloint2double((1023 + dl) << 20, 0);
    aM0 *= sc; aM1 *= sc; aM2 *= sc;
    aI0 *= sc; aI1 *= sc; aI2 *= sc;
  };

  if (role == 0) {
    // ---------------- forward wave: em(0) init + steps em 1..135 ----------
    double tmx[3], tix[3], te0m[3], te0i[3], te1m[3], te1i[3],
           en0[3], en1[3], stpd[3], i0v[3], i1v[3];
#pragma unroll
    for (int j = 0; j < 3; ++j) {
      int mp = mp0 + j;
      bool ok = mp < MT;
      int ix = ok ? mp : 0;
      tmx[j]  = ok ? tabd[T_TMX  *MT+ix] : 0.0;
      tix[j]  = ok ? tabd[T_TIX  *MT+ix] : 0.0;
      te0m[j] = ok ? tabd[T_TMEQ0*MT+ix] : 0.0;
      te0i[j] = ok ? tabd[T_TIEQ0*MT+ix] : 0.0;
      te1m[j] = ok ? tabd[T_TMEQ1*MT+ix] : 0.0;
      te1i[j] = ok ? tabd[T_TIEQ1*MT+ix] : 0.0;
      en0[j]  = ok ? tabd[T_ENT0 *MT+ix] : 0.0;
      en1[j]  = ok ? tabd[T_ENT1 *MT+ix] : 0.0;
      stpd[j] = ok ? tabd[T_STP  *MT+ix] : 0.0;
      i0v[j]  = ok ? tabd[T_I0   *MT+ix] : 0.0;
      i1v[j]  = ok ? tabd[T_I1   *MT+ix] : 0.0;
    }
    double stp0  = stpd[0], stp1 = stpd[1];
    double s2v   = stpd[2];
    double s12   = stpd[1]*stpd[2];
    double stp01 = stpd[0]*stpd[1];
    // pin loop-invariant tables into VGPRs (no remat inside the loop)
    PIN3(tmx);  PIN3(tix);  PIN3(te0m); PIN3(te0i);
    PIN3(te1m); PIN3(te1i); PIN3(en0);  PIN3(en1);
    PIN1(stp0); PIN1(stp1); PIN1(s2v);  PIN1(s12);  PIN1(stp01);

    {
      E6 e0 = loadEoff(ldsTs[0]);
      aM0 = i0v[0]*e0.a.x;  aI0 = i1v[0]*e0.a.y;
      aM1 = i0v[1]*e0.b.x;  aI1 = i1v[1]*e0.b.y;
      aM2 = i0v[2]*e0.c.x;  aI2 = i1v[2]*e0.c.y;
    }

    auto STEP = [&](const E6& cur) {          // r8-proven k<=5 truncation
      const double em0 = cur.a.x, em1 = cur.b.x, em2 = cur.c.x;
      const double ei0 = cur.a.y, ei1 = cur.b.y, ei2 = cur.c.y;
      double ap0 = dpp_d<0x138, 0xF, true>(aM2);
      double xi0 = aI0*tix[0], xi1 = aI1*tix[1], xi2 = aI2*tix[2];
      double X1  = fma(aM0, tmx[1], xi1);
      double X2  = fma(aM1, tmx[2], xi2);
      double xx  = fma(X1, s2v, X2);
      double e01 = fma(aM0, te0m[1], aI1*te0i[1]);
      double e02 = fma(aM1, te0m[2], aI2*te0i[2]);
      double e11 = fma(aM0, te1m[1], aI1*te1i[1]);
      double e12 = fma(aM1, te1m[2], aI2*te1i[2]);
      double g02 = en0[2]*em2, q02 = e02*em2;
      double e00 = fma(ap0, te0m[0], aI0*te0i[0]);
      double e10 = fma(ap0, te1m[0], aI0*te1i[0]);
      double X0  = fma(ap0, tmx[0], xi0);
      double x   = fma(X0, s12, xx);
      double pre = fma(X0, stp1, X1);
      double C0  = dpp_d<0x138, 0xF, true>(x);
      double C1  = fma(C0, stp0,  X0);
      double C2  = fma(C0, stp01, pre);
      aM2 = fma(C2, g02, q02);
      aM0 = fma(C0, en0[0], e00) * em0;
      aM1 = fma(C1, en0[1], e01) * em1;
      aI0 = fma(C0, en1[0], e10) * ei0;
      aI1 = fma(C1, en1[1], e11) * ei1;
      aI2 = fma(C2, en1[2], e12) * ei2;
    };

    E6 bb0 = loadEoff(ldsTs[1]), bb1 = loadEoff(ldsTs[2]), bb2 = loadEoff(ldsTs[3]);
    int of0 = ldsTs[4], of1 = ldsTs[5], of2 = ldsTs[6];
    for (int g = 0; g < 9; ++g) {           // 9 x 15 = 135 steps
      const int tb = 1 + g*15;
#pragma unroll
      for (int k = 0; k < 15; k += 3) {
        STEP(bb0);  bb0 = loadEoff(of0);  of0 = ldsTs[tb + k + 6];
        STEP(bb1);  bb1 = loadEoff(of1);  of1 = ldsTs[tb + k + 7];
        STEP(bb2);  bb2 = loadEoff(of2);  of2 = ldsTs[tb + k + 8];
      }
      RENORM();
    }
  } else {
    // ---------------- backward wave: em 255 .. 136 (120 steps) ------------
    double en0b[3], en1b[3], stpb[3], ti0b[3], ti1b[3], tixb[3],
           tm0s[3], tm1s[3], tmxs[3];
#pragma unroll
    for (int j = 0; j < 3; ++j) {
      int mp = mp0 + j;
      bool ok  = mp < MT;
      bool okp = mp + 1 < MT;
      int ix  = ok  ? mp     : 0;
      int ixp = okp ? mp + 1 : 0;
      en0b[j] = ok  ? tabd[T_ENT0 *MT+ix ] : 0.0;
      en1b[j] = ok  ? tabd[T_ENT1 *MT+ix ] : 0.0;
      stpb[j] = ok  ? tabd[T_STP  *MT+ix ] : 0.0;
      ti0b[j] = ok  ? tabd[T_TIEQ0*MT+ix ] : 0.0;
      ti1b[j] = ok  ? tabd[T_TIEQ1*MT+ix ] : 0.0;
      tixb[j] = ok  ? tabd[T_TIX  *MT+ix ] : 0.0;
      tm0s[j] = okp ? tabd[T_TMEQ0*MT+ixp] : 0.0;   // tables at index mp+1
      tm1s[j] = okp ? tabd[T_TMEQ1*MT+ixp] : 0.0;
      tmxs[j] = okp ? tabd[T_TMX  *MT+ixp] : 0.0;
      double w = ok ? tabd[T_W    *MT+ix ] : 0.0;
      if (j == 0) { aM0 = w; aI0 = w; }
      if (j == 1) { aM1 = w; aI1 = w; }
      if (j == 2) { aM2 = w; aI2 = w; }
    }
    acc2i = 923;   // stored gamma = true * 2^-923
    // pin loop-invariant tables into VGPRs (no remat inside the loop)
    PIN3(en0b); PIN3(en1b); PIN3(stpb);
    PIN3(ti0b); PIN3(ti1b); PIN3(tixb);
    PIN3(tm0s); PIN3(tm1s); PIN3(tmxs);

    auto BSTEP = [&](const E6& cur) {   // transpose step, r11-proven
      double dM0 = aM0*cur.a.x, dI0 = aI0*cur.a.y;
      double dM1 = aM1*cur.b.x, dI1 = aI1*cur.b.y;
      double dM2 = aM2*cur.c.x, dI2 = aI2*cur.c.y;
      double q0 = fma(en0b[0], dM0, en1b[0]*dI0);
      double q1 = fma(en0b[1], dM1, en1b[1]*dI1);
      double q2 = fma(en0b[2], dM2, en1b[2]*dI2);
      double y  = fma(stpb[0], fma(stpb[1], q2, q1), q0);
      double B  = dpp_d<0x130, 0xF, true>(y);        // wave_shl:1, lane63 -> 0
      double dMn= dpp_d<0x130, 0xF, true>(dM0);
      double dIn= dpp_d<0x130, 0xF, true>(dI0);
      double Q2 = B;
      double Q1 = fma(stpb[2], Q2, q2);
      double Q0 = fma(stpb[1], Q1, q1);
      aM0 = fma(tm0s[0], dM1, fma(tm1s[0], dI1, tmxs[0]*Q0));
      aM1 = fma(tm0s[1], dM2, fma(tm1s[1], dI2, tmxs[1]*Q1));
      aM2 = fma(tm0s[2], dMn, fma(tm1s[2], dIn, tmxs[2]*Q2));
      aI0 = fma(ti0b[0], dM0, fma(ti1b[0], dI0, tixb[0]*Q0));
      aI1 = fma(ti0b[1], dM1, fma(ti1b[1], dI1, tixb[1]*Q1));
      aI2 = fma(ti0b[2], dM2, fma(ti1b[2], dI2, tixb[2]*Q2));
    };

    E6 cc0 = loadEoff(ldsTs[255]), cc1 = loadEoff(ldsTs[254]), cc2 = loadEoff(ldsTs[253]);
    int p0 = ldsTs[252], p1 = ldsTs[251], p2 = ldsTs[250];
    for (int g = 0; g < 8; ++g) {           // 8 x 15 = 120 steps
      const int ub = 255 - g*15;
#pragma unroll
      for (int k = 0; k < 15; k += 3) {
        BSTEP(cc0);  cc0 = loadEoff(p0);  p0 = ldsTs[ub - k - 6];
        BSTEP(cc1);  cc1 = loadEoff(p1);  p1 = ldsTs[ub - k - 7];
        BSTEP(cc2);  cc2 = loadEoff(p2);  p2 = ldsTs[ub - k - 8];
      }
      RENORM();
    }
    // hand off gamma(135) + exponent
    gbuf[s][lane*6+0] = aM0;  gbuf[s][lane*6+1] = aM1;  gbuf[s][lane*6+2] = aM2;
    gbuf[s][lane*6+3] = aI0;  gbuf[s][lane*6+4] = aI1;  gbuf[s][lane*6+5] = aI2;
    if (lane == 0) gacc[s] = acc2i;
  }
  __syncthreads();

  if (role == 0) {
    double av[6] = {aM0, aM1, aM2, aI0, aI1, aI2};
    double l2[6];
#pragma unroll
    for (int j = 0; j < 6; ++j) {
      double g = gbuf[s][lane*6+j];
      l2[j] = (av[j] > 0.0 && g > 0.0) ? log2(av[j]) + log2(g) : -1.0e300;
    }
    double lm = l2[0];
#pragma unroll
    for (int j = 1; j < 6; ++j) lm = fmax(lm, l2[j]);
#pragma unroll
    for (int r = 0; r < 6; ++r) lm = fmax(lm, __shfl_xor(lm, 1 << r));
    lm = fmax(lm, -1.0e280);
    double ss = 0.0;
#pragma unroll
    for (int j = 0; j < 6; ++j) ss += exp2(l2[j] - lm);
#pragma unroll
    for (int r = 0; r < 6; ++r) ss += __shfl_xor(ss, 1 << r);
    if (lane == 0) {
      out[n] = (float)(LN2*(lm + log2(ss) + (double)acc2i + (double)gacc[s])
                       - 255.0*BETA);
    }
  }
}

// ---------------------------------------------------------------- launch --
extern "C" void kernel_launch(void* const* d_in, const int* in_sizes, int n_in,
                              void* d_out, int out_size, void* d_ws, size_t ws_size,
                              hipStream_t stream) {
  const float* anc  = (const float*)d_in[0];
  const float* insq = (const float*)d_in[1];
  const float* rr   = (const float*)d_in[2];
  const float* uu   = (const float*)d_in[3];
  const float* data = (const float*)d_in[4];
  float* out = (float*)d_out;

  double* tabd = (double*)d_ws;
  double* emd  = (double*)((char*)d_ws + EMD_OFF);

  hipLaunchKernelGGL(prep_kernel, dim3(1),      dim3(256), 0, stream,
                     anc, insq, rr, uu, tabd, emd);
  hipLaunchKernelGGL(fb_kernel,   dim3(NSEQ/2), dim3(256), 0, stream,
                     tabd, emd, data, out);
}

// Round 18
// 39.841 us; speedup vs baseline: 1.0082x; 1.0082x over previous
//
#include <hip/hip_runtime.h>

#define MT    132
#define NSEQ  512
#define LSEQ  256
#define MM    128      // M
#define NROW  129      // M+1
#define BETA  10.0     // reweighting: track a * e^{BETA*(t - mp)}
#define LOG2E 1.4426950408889634
#define LN2   0.6931471805599453

enum { T_TMX=0, T_TIX, T_TMEQ0, T_TIEQ0, T_TMEQ1, T_TIEQ1,
       T_ENT0, T_ENT1, T_STP, T_I0, T_I1, T_W, T_COUNT };     // 12

#define TABD_CNT   (T_COUNT*MT)
#define EMD_OFF    (TABD_CNT*8)
// emission layout (conflict-free, r14): emd2[tok][j][lane], double2
// {match,ins}, col = 3*lane + j, lane 0..43. Row = 2112 B.
#define EMD_CNT    (25*3*44*2)            // 6600 doubles = 52800 B
#define EMD_ROW_B  (3*44*16)              // 2112 B per token row
#define EMD_J_B    (44*16)                // 704 B per j-block

// DPP ctrl (gfx9/CDNA): WAVE_SHR1=0x138, WAVE_SHL1=0x130, ROW_SHR:d=0x110+d,
// ROW_BCAST15/31=0x142/3. HW-verified rounds 4-16 (absmax 0.0).
template <int CTRL, int RMASK, bool BC>
__device__ __forceinline__ double dpp_d(double v) {
  int lo = __double2loint(v), hi = __double2hiint(v);
  lo = __builtin_amdgcn_update_dpp(0, lo, CTRL, RMASK, 0xF, BC);
  hi = __builtin_amdgcn_update_dpp(0, hi, CTRL, RMASK, 0xF, BC);
  return __hiloint2double(hi, lo);
}

__device__ __forceinline__ double lse2d(double a, double b) {
  double m = fmax(a, b);
  return m + log(exp(a - m) + exp(b - m));
}

// ---- hand-counted LDS pipeline (r17/r18: bypass compiler lgkmcnt) ----
// All in-loop LDS ops are asm volatile (program-order preserved; DS ops
// complete in order per wave). 4 ops/step (1 b32 token + 3 b128 emission).
// lgkmcnt(8) tolerates the last 2 steps' ops; everything older is complete,
// so values read 3 steps ahead are guaranteed landed. Rule-#18 fence:
// sched_barrier(0) right after the wait stops register-only consumers from
// being hoisted above it (no tied 128-bit asm operands needed).
#define TOKRD(dst, taddr, imm) \
  asm volatile("ds_read_b32 %0, %1 offset:%2" \
               : "=&v"(dst) : "v"(taddr), "i"(imm))
#define EMRD(q0, q1, q2, addr) \
  asm volatile("ds_read_b128 %0, %3\n\t" \
               "ds_read_b128 %1, %3 offset:704\n\t" \
               "ds_read_b128 %2, %3 offset:1408" \
               : "=&v"(q0), "=&v"(q1), "=&v"(q2) : "v"(addr))
#define EWAIT() \
  do { asm volatile("s_waitcnt lgkmcnt(8)" ::: "memory"); \
       __builtin_amdgcn_sched_barrier(0); } while (0)

// -------------------------------------------------------------- prep ------
__global__ void prep_kernel(const float* __restrict__ anc,
                            const float* __restrict__ insq,
                            const float* __restrict__ rr,
                            const float* __restrict__ uu,
                            double* __restrict__ tabd,
                            double* __restrict__ emd) {
  const int tid = threadIdx.x;
  __shared__ double ls[T_COUNT*MT];
  if (tid < MT) {
    double v[T_COUNT];
#pragma unroll
    for (int k = 0; k < T_COUNT; ++k) v[k] = 0.0;
    if (tid <= MM) {
      const int m = tid;
      double rn[3][2], un[3][2];
#pragma unroll
      for (int j = 0; j < 3; ++j) {
        double a0 = (double)rr[(m*3+j)*2+0], a1 = (double)rr[(m*3+j)*2+1];
        double l  = lse2d(a0, a1);
        rn[j][0] = a0 - l; rn[j][1] = a1 - l;
        double b0 = (double)uu[(m*3+j)*2+0], b1 = (double)uu[(m*3+j)*2+1];
        double l2 = lse2d(b0, b1);
        un[j][0] = b0 - l2; un[j][1] = b1 - l2;
      }
      v[T_TMX]   = exp(rn[0][0] + un[0][1] - BETA);
      v[T_TIX]   = exp(rn[1][0] + un[1][1]);
      v[T_TMEQ0] = exp(rn[0][0] + un[0][0]);
      v[T_TIEQ0] = exp(rn[1][0] + un[1][0] + BETA);
      v[T_TMEQ1] = exp(rn[0][1]);
      v[T_TIEQ1] = exp(rn[1][1] + BETA);
      v[T_ENT0]  = exp(rn[2][0] + un[2][0]);
      v[T_ENT1]  = exp(rn[2][1]);
      v[T_STP]   = exp(rn[2][0] + un[2][1] - BETA);
      v[T_W]     = exp2(BETA*LOG2E*(double)m - 923.0);
    }
#pragma unroll
    for (int k = 0; k < T_COUNT; ++k) ls[k*MT + tid] = v[k];
  }
  __syncthreads();

  if (tid == 0) {   // initial dist (virtual source i=0,j=0): EXACT full chain
    ls[T_I0*MT+0] = ls[T_TMEQ0*MT+0];
    ls[T_I1*MT+0] = ls[T_TMEQ1*MT+0];
    double c = ls[T_TMX*MT+0];
    for (int mp = 1; mp <= MM; ++mp) {
      ls[T_I0*MT+mp] = c * ls[T_ENT0*MT+mp];
      ls[T_I1*MT+mp] = c * ls[T_ENT1*MT+mp];
      c *= ls[T_STP*MT+mp];
    }
  }
  __syncthreads();

  for (int i = tid; i < T_COUNT*MT; i += blockDim.x) tabd[i] = ls[i];

  if (tid < MT) {
    const int col = tid, j = col % 3, ln = col / 3;
    double2* dst = ((double2*)emd) + (j*44 + ln);
    if (col <= MM) {
      const float* sa = anc  + col*24;
      const float* si = insq + col*24;
      float mxa = -1e30f, mxi = -1e30f;
      for (int d = 0; d < 24; ++d) { mxa = fmaxf(mxa, sa[d]); mxi = fmaxf(mxi, si[d]); }
      float ssa = 0.f, ssi = 0.f;
      for (int d = 0; d < 24; ++d) { ssa += __expf(sa[d]-mxa); ssi += __expf(si[d]-mxi); }
      float ia = 1.f/ssa, ii = 1.f/ssi;
      for (int d = 0; d < 24; ++d) {
        double2 e;
        e.x = (double)(__expf(sa[d]-mxa)*ia);
        e.y = (double)(__expf(si[d]-mxi)*ii);
        dst[d*132] = e;
      }
      double2 one; one.x = 1.0; one.y = 1.0;
      dst[24*132] = one;
    } else {
      double2 z; z.x = 0.0; z.y = 0.0;
      for (int d = 0; d < 25; ++d) dst[d*132] = z;
    }
  }
}

// ------------------------------------------------------------- fwd/bwd ----
struct E6 { double2 a, b, c; };

__global__ __launch_bounds__(256, 1)
void fb_kernel(const double* __restrict__ tabd,
               const double* __restrict__ emd,
               const float* __restrict__ data,
               float* __restrict__ out) {
  __shared__ double2 ldsE[EMD_CNT/2];
  __shared__ int     ldsT[2][LSEQ];
  __shared__ double  gbuf[2][64*6];
  __shared__ int     gacc[2];
  const int tid  = threadIdx.x;
  const int lane = tid & 63;
  const int wid  = tid >> 6;
  const int s    = wid >> 1;
  const int role = wid & 1;
  const int n    = blockIdx.x*2 + s;

  {
    const double2* src = (const double2*)emd;
    for (int i = tid; i < EMD_CNT/2; i += 256) ldsE[i] = src[i];
  }
  for (int pos = tid; pos < 2*LSEQ; pos += 256) {
    const int sq = pos >> 8, pp = pos & (LSEQ-1);
    const float4* p = (const float4*)(data + ((size_t)(blockIdx.x*2 + sq)*LSEQ + pp)*24);
    int tok = 24;
#pragma unroll
    for (int q = 0; q < 6; ++q) {
      float4 v = p[q];
      if (v.x > 0.5f) tok = 4*q+0;
      if (v.y > 0.5f) tok = 4*q+1;
      if (v.z > 0.5f) tok = 4*q+2;
      if (v.w > 0.5f) tok = 4*q+3;
    }
    ldsT[sq][pp] = tok * EMD_ROW_B;
  }
  __syncthreads();

  const int* ldsTs = ldsT[s];
  const int mp0 = 3*lane;
  const int lx  = (lane < 44) ? lane : 43;
  const char* lB = (const char*)ldsE + (size_t)lx*16;
  const uint32_t ebase = (uint32_t)(uintptr_t)lB;        // LDS byte offset
  const uint32_t tbase = (uint32_t)(uintptr_t)&ldsTs[0];
  auto loadEoff = [&](int off) {
    E6 e;
    e.a = *(const double2*)(lB + off);
    e.b = *(const double2*)(lB + off + EMD_J_B);
    e.c = *(const double2*)(lB + off + 2*EMD_J_B);
    return e;
  };

  double aM0, aM1, aM2, aI0, aI1, aI2;
  int acc2i = 0;

  auto RENORM = [&]() {
    double m = fmax(fmax(fmax(aM0,aM1), fmax(aM2,aI0)), fmax(aI1,aI2));
    m = fmax(m, dpp_d<0x111, 0xF, true >(m));
    m = fmax(m, dpp_d<0x112, 0xF, true >(m));
    m = fmax(m, dpp_d<0x114, 0xF, true >(m));
    m = fmax(m, dpp_d<0x118, 0xF, true >(m));
    m = fmax(m, dpp_d<0x142, 0xA, false>(m));
    m = fmax(m, dpp_d<0x143, 0xC, false>(m));
    int ehi = __builtin_amdgcn_readlane(__double2hiint(m), 63);
    int er  = (ehi >> 20) & 0x7FF;
    int dl  = er ? (1523 - er) : 0;
    acc2i -= dl;
    double sc = __hiloint2double((1023 + dl) << 20, 0);
    aM0 *= sc; aM1 *= sc; aM2 *= sc;
    aI0 *= sc; aI1 *= sc; aI2 *= sc;
  };

  int4     eq[4][3];     // emission ring (4 deep), constant-indexed only
  uint32_t ofs[6];       // token-offset ring (6 deep)

  if (role == 0) {
    // -------- forward: em(0) init, prelude em 1..3, asm loop em 4..135 ----
    double tmx[3], tix[3], te0m[3], te0i[3], te1m[3], te1i[3],
           en0[3], en1[3], stpd[3], i0v[3], i1v[3];
#pragma unroll
    for (int j = 0; j < 3; ++j) {
      int mp = mp0 + j;
      bool ok = mp < MT;
      int ix = ok ? mp : 0;
      tmx[j]  = ok ? tabd[T_TMX  *MT+ix] : 0.0;
      tix[j]  = ok ? tabd[T_TIX  *MT+ix] : 0.0;
      te0m[j] = ok ? tabd[T_TMEQ0*MT+ix] : 0.0;
      te0i[j] = ok ? tabd[T_TIEQ0*MT+ix] : 0.0;
      te1m[j] = ok ? tabd[T_TMEQ1*MT+ix] : 0.0;
      te1i[j] = ok ? tabd[T_TIEQ1*MT+ix] : 0.0;
      en0[j]  = ok ? tabd[T_ENT0 *MT+ix] : 0.0;
      en1[j]  = ok ? tabd[T_ENT1 *MT+ix] : 0.0;
      stpd[j] = ok ? tabd[T_STP  *MT+ix] : 0.0;
      i0v[j]  = ok ? tabd[T_I0   *MT+ix] : 0.0;
      i1v[j]  = ok ? tabd[T_I1   *MT+ix] : 0.0;
    }
    const double stp0  = stpd[0], stp1 = stpd[1];
    const double s2v   = stpd[2];
    const double s12   = stpd[1]*stpd[2];
    const double stp01 = stpd[0]*stpd[1];

    {
      E6 e0 = loadEoff(ldsTs[0]);
      aM0 = i0v[0]*e0.a.x;  aI0 = i1v[0]*e0.a.y;
      aM1 = i0v[1]*e0.b.x;  aI1 = i1v[1]*e0.b.y;
      aM2 = i0v[2]*e0.c.x;  aI2 = i1v[2]*e0.c.y;
    }

    auto STEP = [&](double2 ca, double2 cb, double2 cc) {
      const double em0 = ca.x, em1 = cb.x, em2 = cc.x;
      const double ei0 = ca.y, ei1 = cb.y, ei2 = cc.y;
      double ap0 = dpp_d<0x138, 0xF, true>(aM2);
      double xi0 = aI0*tix[0], xi1 = aI1*tix[1], xi2 = aI2*tix[2];
      double X1  = fma(aM0, tmx[1], xi1);
      double X2  = fma(aM1, tmx[2], xi2);
      double xx  = fma(X1, s2v, X2);
      double e01 = fma(aM0, te0m[1], aI1*te0i[1]);
      double e02 = fma(aM1, te0m[2], aI2*te0i[2]);
      double e11 = fma(aM0, te1m[1], aI1*te1i[1]);
      double e12 = fma(aM1, te1m[2], aI2*te1i[2]);
      double g02 = en0[2]*em2, q02 = e02*em2;
      double e00 = fma(ap0, te0m[0], aI0*te0i[0]);
      double e10 = fma(ap0, te1m[0], aI0*te1i[0]);
      double X0  = fma(ap0, tmx[0], xi0);
      double x   = fma(X0, s12, xx);
      double pre = fma(X0, stp1, X1);
      double C0  = dpp_d<0x138, 0xF, true>(x);
      double C1  = fma(C0, stp0,  X0);
      double C2  = fma(C0, stp01, pre);
      aM2 = fma(C2, g02, q02);
      aM0 = fma(C0, en0[0], e00) * em0;
      aM1 = fma(C1, en0[1], e01) * em1;
      aI0 = fma(C0, en1[0], e10) * ei0;
      aI1 = fma(C1, en1[1], e11) * ei1;
      aI2 = fma(C2, en1[2], e12) * ei2;
    };

    for (int t = 1; t <= 3; ++t) {          // slow prelude (compiler waits)
      E6 e = loadEoff(ldsTs[t]);
      STEP(e.a, e.b, e.c);
    }
    // asm-loop prologue: t0 = 4
    ofs[3] = (uint32_t)ldsTs[7];
    ofs[4] = (uint32_t)ldsTs[8];
    ofs[5] = (uint32_t)ldsTs[9];
    EMRD(eq[0][0], eq[0][1], eq[0][2], ebase + (uint32_t)ldsTs[4]);
    EMRD(eq[1][0], eq[1][1], eq[1][2], ebase + (uint32_t)ldsTs[5]);
    EMRD(eq[2][0], eq[2][1], eq[2][2], ebase + (uint32_t)ldsTs[6]);
    int tb = 4;
    for (int g = 0; g < 11; ++g) {          // 11 x 12 = 132 steps (em 4..135)
      const uint32_t ta = tbase + 4u*(uint32_t)(tb + 6);
#pragma unroll
      for (int j = 0; j < 12; ++j) {
        TOKRD(ofs[j%6], ta, 4*j);
        EMRD(eq[(j+3)%4][0], eq[(j+3)%4][1], eq[(j+3)%4][2],
             ebase + ofs[(j+3)%6]);
        EWAIT();
        double2 ca, cb, cc;
        __builtin_memcpy(&ca, &eq[j%4][0], 16);
        __builtin_memcpy(&cb, &eq[j%4][1], 16);
        __builtin_memcpy(&cc, &eq[j%4][2], 16);
        STEP(ca, cb, cc);
      }
      RENORM();
      tb += 12;
    }
  } else {
    // -------- backward: asm loop em 255..136 (10 x 12 steps) --------------
    double en0b[3], en1b[3], stpb[3], ti0b[3], ti1b[3], tixb[3],
           tm0s[3], tm1s[3], tmxs[3];
#pragma unroll
    for (int j = 0; j < 3; ++j) {
      int mp = mp0 + j;
      bool ok  = mp < MT;
      bool okp = mp + 1 < MT;
      int ix  = ok  ? mp     : 0;
      int ixp = okp ? mp + 1 : 0;
      en0b[j] = ok  ? tabd[T_ENT0 *MT+ix ] : 0.0;
      en1b[j] = ok  ? tabd[T_ENT1 *MT+ix ] : 0.0;
      stpb[j] = ok  ? tabd[T_STP  *MT+ix ] : 0.0;
      ti0b[j] = ok  ? tabd[T_TIEQ0*MT+ix ] : 0.0;
      ti1b[j] = ok  ? tabd[T_TIEQ1*MT+ix ] : 0.0;
      tixb[j] = ok  ? tabd[T_TIX  *MT+ix ] : 0.0;
      tm0s[j] = okp ? tabd[T_TMEQ0*MT+ixp] : 0.0;
      tm1s[j] = okp ? tabd[T_TMEQ1*MT+ixp] : 0.0;
      tmxs[j] = okp ? tabd[T_TMX  *MT+ixp] : 0.0;
      double w = ok ? tabd[T_W    *MT+ix ] : 0.0;
      if (j == 0) { aM0 = w; aI0 = w; }
      if (j == 1) { aM1 = w; aI1 = w; }
      if (j == 2) { aM2 = w; aI2 = w; }
    }
    acc2i = 923;

    auto BSTEP = [&](double2 ca, double2 cb, double2 cc) {
      double dM0 = aM0*ca.x, dI0 = aI0*ca.y;
      double dM1 = aM1*cb.x, dI1 = aI1*cb.y;
      double dM2 = aM2*cc.x, dI2 = aI2*cc.y;
      double q0 = fma(en0b[0], dM0, en1b[0]*dI0);
      double q1 = fma(en0b[1], dM1, en1b[1]*dI1);
      double q2 = fma(en0b[2], dM2, en1b[2]*dI2);
      double y  = fma(stpb[0], fma(stpb[1], q2, q1), q0);
      double B  = dpp_d<0x130, 0xF, true>(y);
      double dMn= dpp_d<0x130, 0xF, true>(dM0);
      double dIn= dpp_d<0x130, 0xF, true>(dI0);
      double Q2 = B;
      double Q1 = fma(stpb[2], Q2, q2);
      double Q0 = fma(stpb[1], Q1, q1);
      aM0 = fma(tm0s[0], dM1, fma(tm1s[0], dI1, tmxs[0]*Q0));
      aM1 = fma(tm0s[1], dM2, fma(tm1s[1], dI2, tmxs[1]*Q1));
      aM2 = fma(tm0s[2], dMn, fma(tm1s[2], dIn, tmxs[2]*Q2));
      aI0 = fma(ti0b[0], dM0, fma(ti1b[0], dI0, tixb[0]*Q0));
      aI1 = fma(ti0b[1], dM1, fma(ti1b[1], dI1, tixb[1]*Q1));
      aI2 = fma(ti0b[2], dM2, fma(ti1b[2], dI2, tixb[2]*Q2));
    };

    // asm-loop prologue: u0 = 255
    ofs[3] = (uint32_t)ldsTs[252];
    ofs[4] = (uint32_t)ldsTs[251];
    ofs[5] = (uint32_t)ldsTs[250];
    EMRD(eq[0][0], eq[0][1], eq[0][2], ebase + (uint32_t)ldsTs[255]);
    EMRD(eq[1][0], eq[1][1], eq[1][2], ebase + (uint32_t)ldsTs[254]);
    EMRD(eq[2][0], eq[2][1], eq[2][2], ebase + (uint32_t)ldsTs[253]);
    int ub = 255;
    for (int g = 0; g < 10; ++g) {          // 10 x 12 = 120 steps (em 255..136)
      const uint32_t ta = tbase + 4u*(uint32_t)(ub - 17);
#pragma unroll
      for (int j = 0; j < 12; ++j) {
        TOKRD(ofs[j%6], ta, 4*(11-j));
        EMRD(eq[(j+3)%4][0], eq[(j+3)%4][1], eq[(j+3)%4][2],
             ebase + ofs[(j+3)%6]);
        EWAIT();
        double2 ca, cb, cc;
        __builtin_memcpy(&ca, &eq[j%4][0], 16);
        __builtin_memcpy(&cb, &eq[j%4][1], 16);
        __builtin_memcpy(&cc, &eq[j%4][2], 16);
        BSTEP(ca, cb, cc);
      }
      RENORM();
      ub -= 12;
    }
    gbuf[s][lane*6+0] = aM0;  gbuf[s][lane*6+1] = aM1;  gbuf[s][lane*6+2] = aM2;
    gbuf[s][lane*6+3] = aI0;  gbuf[s][lane*6+4] = aI1;  gbuf[s][lane*6+5] = aI2;
    if (lane == 0) gacc[s] = acc2i;
  }
  __syncthreads();

  if (role == 0) {
    double av[6] = {aM0, aM1, aM2, aI0, aI1, aI2};
    double l2[6];
#pragma unroll
    for (int j = 0; j < 6; ++j) {
      double g = gbuf[s][lane*6+j];
      l2[j] = (av[j] > 0.0 && g > 0.0) ? log2(av[j]) + log2(g) : -1.0e300;
    }
    double lm = l2[0];
#pragma unroll
    for (int j = 1; j < 6; ++j) lm = fmax(lm, l2[j]);
#pragma unroll
    for (int r = 0; r < 6; ++r) lm = fmax(lm, __shfl_xor(lm, 1 << r));
    lm = fmax(lm, -1.0e280);
    double ss = 0.0;
#pragma unroll
    for (int j = 0; j < 6; ++j) ss += exp2(l2[j] - lm);
#pragma unroll
    for (int r = 0; r < 6; ++r) ss += __shfl_xor(ss, 1 << r);
    if (lane == 0) {
      out[n] = (float)(LN2*(lm + log2(ss) + (double)acc2i + (double)gacc[s])
                       - 255.0*BETA);
    }
  }
}

// ---------------------------------------------------------------- launch --
extern "C" void kernel_launch(void* const* d_in, const int* in_sizes, int n_in,
                              void* d_out, int out_size, void* d_ws, size_t ws_size,
                              hipStream_t stream) {
  const float* anc  = (const float*)d_in[0];
  const float* insq = (const float*)d_in[1];
  const float* rr   = (const float*)d_in[2];
  const float* uu   = (const float*)d_in[3];
  const float* data = (const float*)d_in[4];
  float* out = (float*)d_out;

  double* tabd = (double*)d_ws;
  double* emd  = (double*)((char*)d_ws + EMD_OFF);

  hipLaunchKernelGGL(prep_kernel, dim3(1),      dim3(256), 0, stream,
                     anc, insq, rr, uu, tabd, emd);
  hipLaunchKernelGGL(fb_kernel,   dim3(NSEQ/2), dim3(256), 0, stream,
                     tabd, emd, data, out);
}